// Round 2
// baseline (1740.758 us; speedup 1.0000x reference)
//
#include <hip/hip_runtime.h>

#define T_STEPS 256
#define H1 5
#define H2 100
#define NS 4   // batch streams per block (share w2 registers, 4x ILP)

// tanh(x) = 1 - 2/(exp(2x)+1); saturates correctly for |x| large.
__device__ __forceinline__ float fast_tanh(float v) {
    float e = __expf(2.0f * v);
    return 1.0f - 2.0f * __builtin_amdgcn_rcpf(e + 1.0f);
}

// One block per 4 batch elements. 128 threads = 2 waves.
// lane j (< 100): owns row j of Whh2/Wih2 in registers; computes h2[j] for all
//   4 streams each step, reading the shared h2 state as uniform float4
//   broadcasts from LDS (conflict-free).
// lanes 100..119: run the 5-dim layer-1 recurrence one step ahead (one (s,i)
//   pair each), off the j-lanes' critical path. x rows live in LDS.
__global__ __launch_bounds__(128) void rnn_fused4(
    const float* __restrict__ x,
    const float* __restrict__ Wih1, const float* __restrict__ Whh1,
    const float* __restrict__ bih1, const float* __restrict__ bhh1,
    const float* __restrict__ Wih2, const float* __restrict__ Whh2,
    const float* __restrict__ bih2, const float* __restrict__ bhh2,
    const float* __restrict__ W3,   const float* __restrict__ b3,
    float* __restrict__ out)
{
    const int bbase = blockIdx.x * NS;
    const int tid   = threadIdx.x;          // 0..127
    const bool jact = (tid < H2);
    const int  jj   = jact ? tid : 0;

    __shared__ __align__(16) float xs[NS * T_STEPS];   // 4 KB
    __shared__ __align__(16) float h2s[2][NS][104];    // double-buffered state
    __shared__ __align__(16) float h1s[2][NS][8];      // padded to 8 (zeros 5..7)

    // ---- preload x: 4 contiguous rows = 1024 floats = 256 float4 ----
    {
        const float4* xg  = reinterpret_cast<const float4*>(x + (size_t)bbase * T_STEPS);
        float4*       xs4 = reinterpret_cast<float4*>(xs);
        xs4[tid]       = xg[tid];
        xs4[tid + 128] = xg[tid + 128];
    }

    // ---- per-lane layer-2 weight row (registers) ----
    float w2[H2];
    #pragma unroll
    for (int k4 = 0; k4 < H2 / 4; ++k4) {
        float4 v = *reinterpret_cast<const float4*>(Whh2 + jj * H2 + 4 * k4);
        w2[4 * k4 + 0] = v.x; w2[4 * k4 + 1] = v.y;
        w2[4 * k4 + 2] = v.z; w2[4 * k4 + 3] = v.w;
    }
    float wi2[8];
    #pragma unroll
    for (int k = 0; k < 8; ++k) wi2[k] = (k < H1) ? Wih2[jj * H1 + k] : 0.0f;
    const float bias2 = bih2[jj] + bhh2[jj];

    // ---- layer-1 lanes: tid 100..119 -> (stream ls, index li) ----
    const int  l1idx = tid - 100;
    const bool l1act = (l1idx >= 0) && (l1idx < NS * H1);
    const int  ls    = l1act ? (l1idx / H1) : 0;
    const int  li    = l1act ? (l1idx % H1) : 0;
    float w1[H1];
    #pragma unroll
    for (int k = 0; k < H1; ++k) w1[k] = Whh1[li * H1 + k];
    const float wi1 = Wih1[li];
    const float b1  = bih1[li] + bhh1[li];

    // ---- zero-init state buffers ----
    {
        float* p2 = &h2s[0][0][0];                 // 2*NS*104 = 832 floats
        for (int i = tid; i < 2 * NS * 104; i += 128) p2[i] = 0.0f;
        float* p1 = &h1s[0][0][0];                 // 2*NS*8 = 64 floats
        if (tid < 2 * NS * 8) p1[tid] = 0.0f;
    }
    __syncthreads();

    // h1_seq[0] = tanh(Wih1*x_0 + bih1 + bhh1)   (h1_{-1} = 0)
    if (l1act) {
        float u = wi1 * xs[ls * T_STEPS + 0] + b1;
        h1s[0][ls][li] = fast_tanh(u);
    }
    __syncthreads();

    // ---- main recurrence ----
    int cur = 0;
    for (int t = 0; t < T_STEPS; ++t) {
        const int nxt = cur ^ 1;

        float a0[NS], a1[NS], a2[NS], a3[NS];
        #pragma unroll
        for (int s = 0; s < NS; ++s) { a0[s] = bias2; a1[s] = 0.f; a2[s] = 0.f; a3[s] = 0.f; }

        // layer-1 input contribution (padded-to-8 broadcast reads)
        #pragma unroll
        for (int s = 0; s < NS; ++s) {
            const float4 hA = *reinterpret_cast<const float4*>(&h1s[cur][s][0]);
            const float4 hB = *reinterpret_cast<const float4*>(&h1s[cur][s][4]);
            a0[s] += wi2[0] * hA.x; a1[s] += wi2[1] * hA.y;
            a2[s] += wi2[2] * hA.z; a3[s] += wi2[3] * hA.w;
            a0[s] += wi2[4] * hB.x; a1[s] += wi2[5] * hB.y;
            a2[s] += wi2[6] * hB.z; a3[s] += wi2[7] * hB.w;
        }

        // recurrent matvec: k-outer, stream-inner for cross-stream ILP
        #pragma unroll
        for (int k4 = 0; k4 < H2 / 4; ++k4) {
            #pragma unroll
            for (int s = 0; s < NS; ++s) {
                const float4 hv = *reinterpret_cast<const float4*>(&h2s[cur][s][4 * k4]);
                a0[s] += w2[4 * k4 + 0] * hv.x;
                a1[s] += w2[4 * k4 + 1] * hv.y;
                a2[s] += w2[4 * k4 + 2] * hv.z;
                a3[s] += w2[4 * k4 + 3] * hv.w;
            }
        }

        float hn[NS];
        #pragma unroll
        for (int s = 0; s < NS; ++s)
            hn[s] = fast_tanh((a0[s] + a1[s]) + (a2[s] + a3[s]));

        // layer-1 recurrence for step t+1 (spare lanes, x from LDS)
        const bool dol1 = l1act && (t + 1 < T_STEPS);
        float u = 0.0f;
        if (dol1) {
            u = wi1 * xs[ls * T_STEPS + (t + 1)] + b1;
            #pragma unroll
            for (int k = 0; k < H1; ++k) u += w1[k] * h1s[cur][ls][k];
            u = fast_tanh(u);
        }

        if (jact) {
            #pragma unroll
            for (int s = 0; s < NS; ++s) h2s[nxt][s][tid] = hn[s];
        }
        if (dol1) h1s[nxt][ls][li] = u;
        __syncthreads();
        cur = nxt;
    }

    // ---- epilogue: out[b] = relu(W3 · h2_last + b3) ----
    if (tid < NS) {
        float sacc = b3[0];
        #pragma unroll 4
        for (int k = 0; k < H2; ++k) sacc += W3[k] * h2s[cur][tid][k];
        out[bbase + tid] = fmaxf(sacc, 0.0f);
    }
}

extern "C" void kernel_launch(void* const* d_in, const int* in_sizes, int n_in,
                              void* d_out, int out_size, void* d_ws, size_t ws_size,
                              hipStream_t stream) {
    const float* x    = (const float*)d_in[0];
    const float* Wih1 = (const float*)d_in[1];
    const float* Whh1 = (const float*)d_in[2];
    const float* bih1 = (const float*)d_in[3];
    const float* bhh1 = (const float*)d_in[4];
    const float* Wih2 = (const float*)d_in[5];
    const float* Whh2 = (const float*)d_in[6];
    const float* bih2 = (const float*)d_in[7];
    const float* bhh2 = (const float*)d_in[8];
    const float* W3   = (const float*)d_in[9];
    const float* b3   = (const float*)d_in[10];
    float* out = (float*)d_out;

    const int B = in_sizes[0] / T_STEPS;   // 4096
    rnn_fused4<<<B / NS, 128, 0, stream>>>(x, Wih1, Whh1, bih1, bhh1,
                                           Wih2, Whh2, bih2, bhh2, W3, b3, out);
}